// Round 2
// baseline (560.183 us; speedup 1.0000x reference)
//
#include <hip/hip_runtime.h>
#include <hip/hip_bf16.h>

#define DIM 2048
#define NH 16
#define HD 128
#define QD 1024
#define TOT 3072
#define BB 2
#define SS 2048
#define NTOK (BB*SS)
#define EPS 1e-5f

typedef __attribute__((ext_vector_type(4))) float f32x4;
typedef __attribute__((ext_vector_type(8))) short short8;
typedef __attribute__((ext_vector_type(8))) unsigned short u16x8;
typedef __attribute__((ext_vector_type(4))) unsigned short u16x4;

__device__ __forceinline__ float b2f(unsigned short u){
    unsigned int x = ((unsigned int)u) << 16;
    return __builtin_bit_cast(float, x);
}
__device__ __forceinline__ unsigned short f2b(float f){
    unsigned int x = __builtin_bit_cast(unsigned int, f);
    x = (x + 0x7fffu + ((x >> 16) & 1u)) >> 16;
    return (unsigned short)x;
}
__device__ __forceinline__ void store_c(float* p, float v){ *p = v; }
__device__ __forceinline__ void store_c(unsigned short* p, float v){ *p = f2b(v); }

#define MFMA16(a,b,c) __builtin_amdgcn_mfma_f32_16x16x32_bf16((a),(b),(c),0,0,0)

// ---------------- K0: f32 -> bf16 convert ----------------
__global__ __launch_bounds__(256) void cvt_f32_bf16(const float* __restrict__ in,
                                                    unsigned short* __restrict__ out, int n8){
    int i = blockIdx.x * blockDim.x + threadIdx.x;
    int stride = gridDim.x * blockDim.x;
    for (; i < n8; i += stride){
        const float4* p = reinterpret_cast<const float4*>(in + (size_t)i * 8);
        float4 a = p[0], b = p[1];
        u16x8 o;
        o[0]=f2b(a.x); o[1]=f2b(a.y); o[2]=f2b(a.z); o[3]=f2b(a.w);
        o[4]=f2b(b.x); o[5]=f2b(b.y); o[6]=f2b(b.z); o[7]=f2b(b.w);
        *reinterpret_cast<u16x8*>(out + (size_t)i * 8) = o;
    }
}

// ---------------- K1: NT GEMM, A[M,K] bf16, B[N,K] bf16, C[M,N] ----------------
template<typename OutT>
__global__ __launch_bounds__(256) void gemm_nt(const unsigned short* __restrict__ A,
                                               const unsigned short* __restrict__ B,
                                               OutT* __restrict__ C, int M, int N, int K){
    __shared__ __attribute__((aligned(16))) unsigned short As[128][72];
    __shared__ __attribute__((aligned(16))) unsigned short Bs[128][72];
    const int t = threadIdx.x;
    const int lane = t & 63;
    const int w = t >> 6;
    const int wr = w >> 1, wc = w & 1;
    const int m0 = blockIdx.y * 128, n0 = blockIdx.x * 128;
    const int l16 = lane & 15, lq = lane >> 4;

    f32x4 acc[4][4];
    const f32x4 z = {0.f, 0.f, 0.f, 0.f};
    #pragma unroll
    for (int m = 0; m < 4; ++m)
        #pragma unroll
        for (int n = 0; n < 4; ++n) acc[m][n] = z;

    for (int kt = 0; kt < K; kt += 64){
        #pragma unroll
        for (int i = 0; i < 4; ++i){
            int c = t + 256 * i;
            int row = c >> 3, c8 = c & 7;
            *reinterpret_cast<u16x8*>(&As[row][c8 * 8]) =
                *reinterpret_cast<const u16x8*>(&A[(size_t)(m0 + row) * K + kt + c8 * 8]);
            *reinterpret_cast<u16x8*>(&Bs[row][c8 * 8]) =
                *reinterpret_cast<const u16x8*>(&B[(size_t)(n0 + row) * K + kt + c8 * 8]);
        }
        __syncthreads();
        #pragma unroll
        for (int kk = 0; kk < 2; ++kk){
            short8 af[4], bf[4];
            #pragma unroll
            for (int m = 0; m < 4; ++m)
                af[m] = *reinterpret_cast<const short8*>(&As[wr*64 + m*16 + l16][kk*32 + lq*8]);
            #pragma unroll
            for (int n = 0; n < 4; ++n)
                bf[n] = *reinterpret_cast<const short8*>(&Bs[wc*64 + n*16 + l16][kk*32 + lq*8]);
            #pragma unroll
            for (int m = 0; m < 4; ++m)
                #pragma unroll
                for (int n = 0; n < 4; ++n)
                    acc[m][n] = MFMA16(af[m], bf[n], acc[m][n]);
        }
        __syncthreads();
    }
    #pragma unroll
    for (int m = 0; m < 4; ++m){
        int grow = m0 + wr*64 + m*16 + lq*4;
        #pragma unroll
        for (int n = 0; n < 4; ++n){
            int gcol = n0 + wc*64 + n*16 + l16;
            #pragma unroll
            for (int r = 0; r < 4; ++r)
                store_c(&C[(size_t)(grow + r) * N + gcol], acc[m][n][r]);
        }
    }
}

// ---------------- K2: qkv postprocess (rmsnorm + rope + concat + cat-rmsnorm) ----------------
__global__ __launch_bounds__(256) void qkv_post(
    const unsigned short* __restrict__ comb_lc, const unsigned short* __restrict__ comb_gc,
    const float* __restrict__ freqs,
    const float* __restrict__ q_lc_nw, const float* __restrict__ k_lc_nw,
    const float* __restrict__ q_gc_nw, const float* __restrict__ k_gc_nw,
    const float* __restrict__ q_cat_nw, const float* __restrict__ k_cat_nw,
    unsigned short* __restrict__ xq, unsigned short* __restrict__ xk,
    unsigned short* __restrict__ xv)
{
    __shared__ float qcat[16][128];
    __shared__ float kcat[16][128];
    __shared__ float rbuf[4][4];
    const int tok = blockIdx.x;
    const int s = tok & (SS - 1);
    const unsigned short* clc = comb_lc + (size_t)tok * TOT;
    const unsigned short* cgc = comb_gc + (size_t)tok * TOT;
    const int t = threadIdx.x;
    const int lane = t & 63, w = t >> 6;

    const unsigned short* segs[4] = { clc, clc + QD, cgc, cgc + QD };
    const float* wts[4] = { q_lc_nw, k_lc_nw, q_gc_nw, k_gc_nw };

    // pass 1: sum of squares per segment
    float ss4[4];
    #pragma unroll
    for (int sg = 0; sg < 4; ++sg){
        u16x4 v = *reinterpret_cast<const u16x4*>(segs[sg] + t * 4);
        float acc = 0.f;
        #pragma unroll
        for (int j = 0; j < 4; ++j){ float f = b2f(v[j]); acc += f * f; }
        ss4[sg] = acc;
    }
    #pragma unroll
    for (int sg = 0; sg < 4; ++sg){
        float v = ss4[sg];
        #pragma unroll
        for (int o = 32; o >= 1; o >>= 1) v += __shfl_xor(v, o);
        if (lane == 0) rbuf[sg][w] = v;
    }
    __syncthreads();
    float rms[4];
    #pragma unroll
    for (int sg = 0; sg < 4; ++sg){
        float tot = rbuf[sg][0] + rbuf[sg][1] + rbuf[sg][2] + rbuf[sg][3];
        rms[sg] = rsqrtf(tot * (1.f / QD) + EPS);
    }

    // pass 2: norm + rope -> LDS concat buffers
    #pragma unroll
    for (int sg = 0; sg < 4; ++sg){
        const unsigned short* seg = segs[sg];
        const float* wt = wts[sg];
        const float rf = rms[sg];
        float (*dst)[128] = (sg == 0 || sg == 2) ? qcat : kcat;
        const int coff = (sg >= 2) ? 64 : 0;
        #pragma unroll
        for (int pi = 0; pi < 2; ++pi){
            int p = t + pi * 256;         // 0..511
            int h = p >> 5, j = p & 31;
            int idx = h * 64 + 2 * j;
            float xr = b2f(seg[idx])     * rf * wt[idx];
            float xi = b2f(seg[idx + 1]) * rf * wt[idx + 1];
            float fr = freqs[(size_t)s * 32 + j];
            float cs = __cosf(fr), sn = __sinf(fr);
            dst[h][coff + 2*j]     = xr * cs - xi * sn;
            dst[h][coff + 2*j + 1] = xr * sn + xi * cs;
        }
    }

    // v pass-through: concat halves into [h][128]
    {
        int i0 = t * 4;
        int h = i0 >> 6, d = i0 & 63;
        u16x4 vlc = *reinterpret_cast<const u16x4*>(clc + 2048 + i0);
        u16x4 vgc = *reinterpret_cast<const u16x4*>(cgc + 2048 + i0);
        *reinterpret_cast<u16x4*>(&xv[(size_t)tok * DIM + h * 128 + d])      = vlc;
        *reinterpret_cast<u16x4*>(&xv[(size_t)tok * DIM + h * 128 + 64 + d]) = vgc;
    }
    __syncthreads();

    // pass 3: cat rmsnorm per head (128) and emit
    {
        int h = t >> 4, sub = t & 15;
        float sq = 0.f, sk = 0.f;
        #pragma unroll
        for (int j = 0; j < 8; ++j){
            float a = qcat[h][sub*8 + j]; sq += a * a;
            float b = kcat[h][sub*8 + j]; sk += b * b;
        }
        #pragma unroll
        for (int o = 1; o < 16; o <<= 1){ sq += __shfl_xor(sq, o); sk += __shfl_xor(sk, o); }
        float rq = rsqrtf(sq * (1.f / 128) + EPS);
        float rk = rsqrtf(sk * (1.f / 128) + EPS);
        u16x8 oq, ok;
        #pragma unroll
        for (int j = 0; j < 8; ++j){
            int d = sub*8 + j;
            oq[j] = f2b(qcat[h][d] * rq * q_cat_nw[d]);
            ok[j] = f2b(kcat[h][d] * rk * k_cat_nw[d]);
        }
        *reinterpret_cast<u16x8*>(&xq[(size_t)tok * DIM + h * 128 + sub*8]) = oq;
        *reinterpret_cast<u16x8*>(&xk[(size_t)tok * DIM + h * 128 + sub*8]) = ok;
    }
}

// ---------------- K4: V transpose -> xvT[b,h,d,s] ----------------
__global__ __launch_bounds__(256) void transpose_v(const unsigned short* __restrict__ xv,
                                                   unsigned short* __restrict__ xvT){
    __shared__ unsigned short tile[128][129];
    const int blk = blockIdx.x;
    const int st = blk & 15;
    const int bh = blk >> 4;
    const int b = bh >> 4, h = bh & 15;
    const int t = threadIdx.x;
    const int s0 = st * 128;
    #pragma unroll
    for (int i = 0; i < 8; ++i){
        int c = t + 256 * i;
        int r = c >> 4, dc = c & 15;
        u16x8 v = *reinterpret_cast<const u16x8*>(&xv[((size_t)(b*SS + s0 + r)) * DIM + h*HD + dc*8]);
        #pragma unroll
        for (int j = 0; j < 8; ++j) tile[r][dc*8 + j] = v[j];
    }
    __syncthreads();
    #pragma unroll
    for (int i = 0; i < 8; ++i){
        int c = t + 256 * i;
        int d = c >> 4, sc = c & 15;
        u16x8 o;
        #pragma unroll
        for (int j = 0; j < 8; ++j) o[j] = tile[sc*8 + j][d];
        *reinterpret_cast<u16x8*>(&xvT[((size_t)bh * HD + d) * SS + s0 + sc*8]) = o;
    }
}

// ---------------- K3: flash attention (no mask) ----------------
__global__ __launch_bounds__(256) void attn_fwd(const unsigned short* __restrict__ xq,
                                                const unsigned short* __restrict__ xk,
                                                const unsigned short* __restrict__ xvT,
                                                unsigned short* __restrict__ attn_out){
    __shared__ __attribute__((aligned(16))) unsigned short Kl[64 * 128];
    __shared__ __attribute__((aligned(16))) unsigned short Vt[128 * 64];
    __shared__ __attribute__((aligned(16))) unsigned short Pl[4][32 * 64];
    const int blk = blockIdx.x;
    const int qt = blk & 15, h = (blk >> 4) & 15, b = blk >> 8;
    const int t = threadIdx.x, lane = t & 63, w = t >> 6;
    const int l16 = lane & 15, lq = lane >> 4;
    const float scale = 0.08838834764831845f;

    // Q fragments in registers (reused across all KV tiles)
    short8 qf[2][4];
    const int qrow_base = qt * 128 + w * 32;
    #pragma unroll
    for (int m = 0; m < 2; ++m)
        #pragma unroll
        for (int ks = 0; ks < 4; ++ks){
            int row = qrow_base + m*16 + l16;
            qf[m][ks] = *reinterpret_cast<const short8*>(
                &xq[((size_t)(b*SS + row)) * DIM + h*HD + ks*32 + lq*8]);
        }

    float mrun[2][4], lrun[2][4];
    f32x4 O[2][8];
    const f32x4 z = {0.f, 0.f, 0.f, 0.f};
    #pragma unroll
    for (int m = 0; m < 2; ++m){
        #pragma unroll
        for (int r = 0; r < 4; ++r){ mrun[m][r] = -INFINITY; lrun[m][r] = 0.f; }
        #pragma unroll
        for (int n = 0; n < 8; ++n) O[m][n] = z;
    }

    for (int kt = 0; kt < SS / 64; ++kt){
        // stage K (64x128) and Vt (128x64), XOR-swizzled 16B chunks
        #pragma unroll
        for (int i = 0; i < 4; ++i){
            int c = t + 256 * i;
            int r = c >> 4, dc = c & 15;
            u16x8 kv = *reinterpret_cast<const u16x8*>(
                &xk[((size_t)(b*SS + kt*64 + r)) * DIM + h*HD + dc*8]);
            *reinterpret_cast<u16x8*>(&Kl[r*128 + ((dc ^ (r & 7)) * 8)]) = kv;
            int d = c >> 3, kc = c & 7;
            u16x8 vv = *reinterpret_cast<const u16x8*>(
                &xvT[((size_t)(b*NH + h) * HD + d) * SS + kt*64 + kc*8]);
            *reinterpret_cast<u16x8*>(&Vt[d*64 + ((kc ^ (d & 7)) * 8)]) = vv;
        }
        __syncthreads();

        // S = Q K^T
        f32x4 S[2][4];
        #pragma unroll
        for (int m = 0; m < 2; ++m)
            #pragma unroll
            for (int n = 0; n < 4; ++n) S[m][n] = z;
        #pragma unroll
        for (int n = 0; n < 4; ++n){
            int krow = n*16 + l16;
            #pragma unroll
            for (int ks = 0; ks < 4; ++ks){
                short8 bk = *reinterpret_cast<const short8*>(
                    &Kl[krow*128 + (((ks*4 + lq) ^ (krow & 7)) * 8)]);
                S[0][n] = MFMA16(qf[0][ks], bk, S[0][n]);
                S[1][n] = MFMA16(qf[1][ks], bk, S[1][n]);
            }
        }

        // online softmax + P to LDS (bf16)
        #pragma unroll
        for (int m = 0; m < 2; ++m){
            #pragma unroll
            for (int r = 0; r < 4; ++r){
                float mx = fmaxf(fmaxf(S[m][0][r], S[m][1][r]), fmaxf(S[m][2][r], S[m][3][r]));
                #pragma unroll
                for (int o = 1; o < 16; o <<= 1) mx = fmaxf(mx, __shfl_xor(mx, o));
                mx *= scale;
                float mnew = fmaxf(mrun[m][r], mx);
                float p[4]; float psum = 0.f;
                #pragma unroll
                for (int n = 0; n < 4; ++n){ p[n] = __expf(S[m][n][r] * scale - mnew); psum += p[n]; }
                #pragma unroll
                for (int o = 1; o < 16; o <<= 1) psum += __shfl_xor(psum, o);
                float alpha = __expf(mrun[m][r] - mnew);
                lrun[m][r] = lrun[m][r] * alpha + psum;
                mrun[m][r] = mnew;
                #pragma unroll
                for (int n = 0; n < 8; ++n) O[m][n][r] *= alpha;
                int prow = m*16 + lq*4 + r;
                #pragma unroll
                for (int n = 0; n < 4; ++n){
                    int col = n*16 + l16;
                    Pl[w][prow*64 + (((col >> 3) ^ (prow & 7)) * 8) + (col & 7)] = f2b(p[n]);
                }
            }
        }
        // same-wave cross-lane LDS visibility for P
        asm volatile("s_waitcnt lgkmcnt(0)" ::: "memory");
        __builtin_amdgcn_sched_barrier(0);

        // O += P V
        #pragma unroll
        for (int kk = 0; kk < 2; ++kk){
            short8 pa[2];
            #pragma unroll
            for (int m = 0; m < 2; ++m){
                int prow = m*16 + l16;
                pa[m] = *reinterpret_cast<const short8*>(
                    &Pl[w][prow*64 + (((kk*4 + lq) ^ (prow & 7)) * 8)]);
            }
            #pragma unroll
            for (int n = 0; n < 8; ++n){
                int drow = n*16 + l16;
                short8 bv = *reinterpret_cast<const short8*>(
                    &Vt[drow*64 + (((kk*4 + lq) ^ (drow & 7)) * 8)]);
                O[0][n] = MFMA16(pa[0], bv, O[0][n]);
                O[1][n] = MFMA16(pa[1], bv, O[1][n]);
            }
        }
        __syncthreads();
    }

    // epilogue: normalize and write
    #pragma unroll
    for (int m = 0; m < 2; ++m)
        #pragma unroll
        for (int r = 0; r < 4; ++r){
            float inv = 1.f / lrun[m][r];
            int qrow = qrow_base + m*16 + lq*4 + r;
            #pragma unroll
            for (int n = 0; n < 8; ++n)
                attn_out[((size_t)(b*SS + qrow)) * DIM + h*HD + n*16 + l16] = f2b(O[m][n][r] * inv);
        }
}

// ---------------- K5: bias + rmsnorm epilogue (bf16 proj input) ----------------
__global__ __launch_bounds__(256) void proj_norm(const unsigned short* __restrict__ proj,
                                                 const float* __restrict__ bias,
                                                 const float* __restrict__ w,
                                                 float* __restrict__ out){
    __shared__ float buf[DIM];
    __shared__ float rbuf[4];
    const int row = blockIdx.x;
    const int t = threadIdx.x;
    const int lane = t & 63, wv = t >> 6;
    float ssq = 0.f;
    #pragma unroll
    for (int i = 0; i < 8; ++i){
        int o = t + i * 256;
        float v = b2f(proj[(size_t)row * DIM + o]) + bias[o];
        buf[o] = v;
        ssq += v * v;
    }
    #pragma unroll
    for (int o = 32; o >= 1; o >>= 1) ssq += __shfl_xor(ssq, o);
    if (lane == 0) rbuf[wv] = ssq;
    __syncthreads();
    float tot = rbuf[0] + rbuf[1] + rbuf[2] + rbuf[3];
    float rr = rsqrtf(tot * (1.f / DIM) + EPS);
    #pragma unroll
    for (int i = 0; i < 8; ++i){
        int o = t + i * 256;
        out[(size_t)row * DIM + o] = buf[o] * rr * w[o];
    }
}

extern "C" void kernel_launch(void* const* d_in, const int* in_sizes, int n_in,
                              void* d_out, int out_size, void* d_ws, size_t ws_size,
                              hipStream_t stream)
{
    const float* local_c  = (const float*)d_in[0];
    const float* global_c = (const float*)d_in[1];
    const float* freqs    = (const float*)d_in[2];
    const float* W_lc     = (const float*)d_in[3];
    const float* W_gc     = (const float*)d_in[4];
    const float* q_lc_nw  = (const float*)d_in[5];
    const float* k_lc_nw  = (const float*)d_in[6];
    const float* q_gc_nw  = (const float*)d_in[7];
    const float* k_gc_nw  = (const float*)d_in[8];
    const float* q_cat_nw = (const float*)d_in[9];
    const float* k_cat_nw = (const float*)d_in[10];
    const float* W_lo     = (const float*)d_in[11];
    const float* b_lo     = (const float*)d_in[12];
    const float* lc_on_w  = (const float*)d_in[13];
    const float* W_go     = (const float*)d_in[14];
    const float* b_go     = (const float*)d_in[15];
    const float* gc_on_w  = (const float*)d_in[16];
    float* out = (float*)d_out;

    // ---- aliased workspace arena: 120 MB total (was 277 MB -> suspected d_ws OOB fault) ----
    char* ws = (char*)d_ws;
    const size_t SZ_WLO  = (size_t)DIM * DIM * 2;    //  8.39 MB
    const size_t SZ_WLC  = (size_t)TOT * DIM * 2;    // 12.58 MB
    const size_t SZ_TOK2 = (size_t)NTOK * DIM * 2;   // 16.78 MB (bf16 token tensor)
    const size_t SZ_COMB = (size_t)NTOK * TOT * 2;   // 25.17 MB

    unsigned short* Wlo_b  = (unsigned short*)(ws);                           // [0, 8.39)      persistent
    unsigned short* Wgo_b  = (unsigned short*)(ws + SZ_WLO);                  // [8.39, 16.78)  persistent
    char*           slotW  = ws + 2*SZ_WLO;                                   // [16.78, 41.94) Wlc+Wgc, then xv
    unsigned short* Wlc_b  = (unsigned short*)(slotW);
    unsigned short* Wgc_b  = (unsigned short*)(slotW + SZ_WLC);
    unsigned short* xv     = (unsigned short*)(slotW);                        // alias (Wlc/Wgc dead after QKV GEMMs)
    char*           slotE  = ws + 2*SZ_WLO + 2*SZ_WLC;                        // [41.94, 58.72)
    char*           slotF  = slotE + SZ_TOK2;                                 // [58.72, 75.50)
    unsigned short* xb_lc  = (unsigned short*)slotE;
    unsigned short* xb_gc  = (unsigned short*)slotF;
    unsigned short* xq     = (unsigned short*)slotE;                          // alias (xb_lc dead)
    unsigned short* xk     = (unsigned short*)slotF;                          // alias (xb_gc dead)
    unsigned short* proj_lc= (unsigned short*)slotE;                          // alias (xq dead after attn)
    unsigned short* proj_gc= (unsigned short*)slotF;                          // alias (xk dead after attn)
    char*           slotG  = slotF + SZ_TOK2;                                 // [75.50, 100.66)
    char*           slotH  = slotG + SZ_COMB;                                 // [100.66, 125.83)
    unsigned short* comb_lc= (unsigned short*)slotG;
    unsigned short* comb_gc= (unsigned short*)slotH;
    unsigned short* xvT    = (unsigned short*)slotG;                          // alias (comb_lc dead after qkv_post)
    unsigned short* attn_o = (unsigned short*)slotH;                          // alias (comb_gc dead after qkv_post)
    (void)ws_size;

    // 1) converts
    cvt_f32_bf16<<<1024, 256, 0, stream>>>(local_c,  xb_lc, NTOK * DIM / 8);
    cvt_f32_bf16<<<1024, 256, 0, stream>>>(global_c, xb_gc, NTOK * DIM / 8);
    cvt_f32_bf16<<<1024, 256, 0, stream>>>(W_lc, Wlc_b, TOT * DIM / 8);
    cvt_f32_bf16<<<1024, 256, 0, stream>>>(W_gc, Wgc_b, TOT * DIM / 8);
    cvt_f32_bf16<<<1024, 256, 0, stream>>>(W_lo, Wlo_b, DIM * DIM / 8);
    cvt_f32_bf16<<<1024, 256, 0, stream>>>(W_go, Wgo_b, DIM * DIM / 8);

    // 2) QKV GEMMs
    dim3 g1(TOT / 128, NTOK / 128);
    gemm_nt<unsigned short><<<g1, 256, 0, stream>>>(xb_lc, Wlc_b, comb_lc, NTOK, TOT, DIM);
    gemm_nt<unsigned short><<<g1, 256, 0, stream>>>(xb_gc, Wgc_b, comb_gc, NTOK, TOT, DIM);

    // 3) norms + rope + concat   (writes xv over dead Wlc/Wgc, xq/xk over dead xb)
    qkv_post<<<NTOK, 256, 0, stream>>>(comb_lc, comb_gc, freqs,
                                       q_lc_nw, k_lc_nw, q_gc_nw, k_gc_nw,
                                       q_cat_nw, k_cat_nw, xq, xk, xv);

    // 4) V transpose   (xvT over dead comb_lc)
    transpose_v<<<512, 256, 0, stream>>>(xv, xvT);

    // 5) attention     (attn_o over dead comb_gc)
    attn_fwd<<<512, 256, 0, stream>>>(xq, xk, xvT, attn_o);

    // 6) output projections (bf16 out, over dead xq/xk)
    dim3 g2(DIM / 128, NTOK / 128);
    gemm_nt<unsigned short><<<g2, 256, 0, stream>>>(attn_o, Wlo_b, proj_lc, NTOK, DIM, DIM);
    gemm_nt<unsigned short><<<g2, 256, 0, stream>>>(attn_o, Wgo_b, proj_gc, NTOK, DIM, DIM);

    // 7) final norms
    proj_norm<<<NTOK, 256, 0, stream>>>(proj_lc, b_lo, lc_on_w, out);
    proj_norm<<<NTOK, 256, 0, stream>>>(proj_gc, b_go, gc_on_w, out + (size_t)NTOK * DIM);
}

// Round 3
// 504.588 us; speedup vs baseline: 1.1102x; 1.1102x over previous
//
#include <hip/hip_runtime.h>
#include <hip/hip_bf16.h>

#define DIM 2048
#define NH 16
#define HD 128
#define QD 1024
#define TOT 3072
#define BB 2
#define SS 2048
#define NTOK (BB*SS)
#define EPS 1e-5f

typedef __attribute__((ext_vector_type(4))) float f32x4;
typedef __attribute__((ext_vector_type(8))) short short8;
typedef __attribute__((ext_vector_type(8))) unsigned short u16x8;
typedef __attribute__((ext_vector_type(4))) unsigned short u16x4;

__device__ __forceinline__ float b2f(unsigned short u){
    unsigned int x = ((unsigned int)u) << 16;
    return __builtin_bit_cast(float, x);
}
__device__ __forceinline__ unsigned short f2b(float f){
    unsigned int x = __builtin_bit_cast(unsigned int, f);
    x = (x + 0x7fffu + ((x >> 16) & 1u)) >> 16;
    return (unsigned short)x;
}
__device__ __forceinline__ void store_c(float* p, float v){ *p = v; }
__device__ __forceinline__ void store_c(unsigned short* p, float v){ *p = f2b(v); }

#define MFMA16(a,b,c) __builtin_amdgcn_mfma_f32_16x16x32_bf16((a),(b),(c),0,0,0)

// async global->LDS, 16B per lane; lds dest must be wave-uniform base (HW adds lane*16)
#define GLOAD16(g, l) __builtin_amdgcn_global_load_lds( \
    (const __attribute__((address_space(1))) unsigned int*)(g), \
    (__attribute__((address_space(3))) unsigned int*)(l), 16, 0, 0)

// ---------------- K0: f32 -> bf16 convert ----------------
__global__ __launch_bounds__(256) void cvt_f32_bf16(const float* __restrict__ in,
                                                    unsigned short* __restrict__ out, int n8){
    int i = blockIdx.x * blockDim.x + threadIdx.x;
    int stride = gridDim.x * blockDim.x;
    for (; i < n8; i += stride){
        const float4* p = reinterpret_cast<const float4*>(in + (size_t)i * 8);
        float4 a = p[0], b = p[1];
        u16x8 o;
        o[0]=f2b(a.x); o[1]=f2b(a.y); o[2]=f2b(a.z); o[3]=f2b(a.w);
        o[4]=f2b(b.x); o[5]=f2b(b.y); o[6]=f2b(b.z); o[7]=f2b(b.w);
        *reinterpret_cast<u16x8*>(out + (size_t)i * 8) = o;
    }
}

// ---------------- K1: NT GEMM, m97-style: global_load_lds w16, linear LDS ----------------
template<typename OutT>
__global__ __launch_bounds__(256) void gemm_nt(const unsigned short* __restrict__ A,
                                               const unsigned short* __restrict__ B,
                                               OutT* __restrict__ C, int M, int N, int K){
    __shared__ __attribute__((aligned(16))) unsigned short As[128*64];
    __shared__ __attribute__((aligned(16))) unsigned short Bs[128*64];
    const int t = threadIdx.x;
    const int lane = t & 63;
    const int w = t >> 6;
    const int wr = w >> 1, wc = w & 1;
    const int m0 = blockIdx.y * 128, n0 = blockIdx.x * 128;
    const int l16 = lane & 15, lq = lane >> 4;

    f32x4 acc[4][4];
    const f32x4 z = {0.f, 0.f, 0.f, 0.f};
    #pragma unroll
    for (int m = 0; m < 4; ++m)
        #pragma unroll
        for (int n = 0; n < 4; ++n) acc[m][n] = z;

    for (int kt = 0; kt < K; kt += 64){
        #pragma unroll
        for (int i = 0; i < 4; ++i){
            int c = t + 256 * i;
            int row = c >> 3, c8 = c & 7;
            GLOAD16(&A[(size_t)(m0 + row) * K + kt + c8 * 8],
                    (char*)As + (size_t)(i * 256 + w * 64) * 16);
            GLOAD16(&B[(size_t)(n0 + row) * K + kt + c8 * 8],
                    (char*)Bs + (size_t)(i * 256 + w * 64) * 16);
        }
        __syncthreads();
        #pragma unroll
        for (int kk = 0; kk < 2; ++kk){
            short8 af[4], bf[4];
            #pragma unroll
            for (int m = 0; m < 4; ++m)
                af[m] = *reinterpret_cast<const short8*>(&As[(wr*64 + m*16 + l16)*64 + kk*32 + lq*8]);
            #pragma unroll
            for (int n = 0; n < 4; ++n)
                bf[n] = *reinterpret_cast<const short8*>(&Bs[(wc*64 + n*16 + l16)*64 + kk*32 + lq*8]);
            #pragma unroll
            for (int m = 0; m < 4; ++m)
                #pragma unroll
                for (int n = 0; n < 4; ++n)
                    acc[m][n] = MFMA16(af[m], bf[n], acc[m][n]);
        }
        __syncthreads();
    }
    #pragma unroll
    for (int m = 0; m < 4; ++m){
        int grow = m0 + wr*64 + m*16 + lq*4;
        #pragma unroll
        for (int n = 0; n < 4; ++n){
            int gcol = n0 + wc*64 + n*16 + l16;
            #pragma unroll
            for (int r = 0; r < 4; ++r)
                store_c(&C[(size_t)(grow + r) * N + gcol], acc[m][n][r]);
        }
    }
}

// ---------------- K2: qkv postprocess (rmsnorm + rope + concat + cat-rmsnorm) ----------------
__global__ __launch_bounds__(256) void qkv_post(
    const unsigned short* __restrict__ comb_lc, const unsigned short* __restrict__ comb_gc,
    const float* __restrict__ freqs,
    const float* __restrict__ q_lc_nw, const float* __restrict__ k_lc_nw,
    const float* __restrict__ q_gc_nw, const float* __restrict__ k_gc_nw,
    const float* __restrict__ q_cat_nw, const float* __restrict__ k_cat_nw,
    unsigned short* __restrict__ xq, unsigned short* __restrict__ xk,
    unsigned short* __restrict__ xv)
{
    __shared__ float qcat[16][128];
    __shared__ float kcat[16][128];
    __shared__ float rbuf[4][4];
    const int tok = blockIdx.x;
    const int s = tok & (SS - 1);
    const unsigned short* clc = comb_lc + (size_t)tok * TOT;
    const unsigned short* cgc = comb_gc + (size_t)tok * TOT;
    const int t = threadIdx.x;
    const int lane = t & 63, w = t >> 6;

    const unsigned short* segs[4] = { clc, clc + QD, cgc, cgc + QD };
    const float* wts[4] = { q_lc_nw, k_lc_nw, q_gc_nw, k_gc_nw };

    float ss4[4];
    #pragma unroll
    for (int sg = 0; sg < 4; ++sg){
        u16x4 v = *reinterpret_cast<const u16x4*>(segs[sg] + t * 4);
        float acc = 0.f;
        #pragma unroll
        for (int j = 0; j < 4; ++j){ float f = b2f(v[j]); acc += f * f; }
        ss4[sg] = acc;
    }
    #pragma unroll
    for (int sg = 0; sg < 4; ++sg){
        float v = ss4[sg];
        #pragma unroll
        for (int o = 32; o >= 1; o >>= 1) v += __shfl_xor(v, o);
        if (lane == 0) rbuf[sg][w] = v;
    }
    __syncthreads();
    float rms[4];
    #pragma unroll
    for (int sg = 0; sg < 4; ++sg){
        float tot = rbuf[sg][0] + rbuf[sg][1] + rbuf[sg][2] + rbuf[sg][3];
        rms[sg] = rsqrtf(tot * (1.f / QD) + EPS);
    }

    #pragma unroll
    for (int sg = 0; sg < 4; ++sg){
        const unsigned short* seg = segs[sg];
        const float* wt = wts[sg];
        const float rf = rms[sg];
        float (*dst)[128] = (sg == 0 || sg == 2) ? qcat : kcat;
        const int coff = (sg >= 2) ? 64 : 0;
        #pragma unroll
        for (int pi = 0; pi < 2; ++pi){
            int p = t + pi * 256;
            int h = p >> 5, j = p & 31;
            int idx = h * 64 + 2 * j;
            float xr = b2f(seg[idx])     * rf * wt[idx];
            float xi = b2f(seg[idx + 1]) * rf * wt[idx + 1];
            float fr = freqs[(size_t)s * 32 + j];
            float cs = __cosf(fr), sn = __sinf(fr);
            dst[h][coff + 2*j]     = xr * cs - xi * sn;
            dst[h][coff + 2*j + 1] = xr * sn + xi * cs;
        }
    }

    {
        int i0 = t * 4;
        int h = i0 >> 6, d = i0 & 63;
        u16x4 vlc = *reinterpret_cast<const u16x4*>(clc + 2048 + i0);
        u16x4 vgc = *reinterpret_cast<const u16x4*>(cgc + 2048 + i0);
        *reinterpret_cast<u16x4*>(&xv[(size_t)tok * DIM + h * 128 + d])      = vlc;
        *reinterpret_cast<u16x4*>(&xv[(size_t)tok * DIM + h * 128 + 64 + d]) = vgc;
    }
    __syncthreads();

    {
        int h = t >> 4, sub = t & 15;
        float sq = 0.f, sk = 0.f;
        #pragma unroll
        for (int j = 0; j < 8; ++j){
            float a = qcat[h][sub*8 + j]; sq += a * a;
            float b = kcat[h][sub*8 + j]; sk += b * b;
        }
        #pragma unroll
        for (int o = 1; o < 16; o <<= 1){ sq += __shfl_xor(sq, o); sk += __shfl_xor(sk, o); }
        float rq = rsqrtf(sq * (1.f / 128) + EPS);
        float rk = rsqrtf(sk * (1.f / 128) + EPS);
        u16x8 oq, ok;
        #pragma unroll
        for (int j = 0; j < 8; ++j){
            int d = sub*8 + j;
            oq[j] = f2b(qcat[h][d] * rq * q_cat_nw[d]);
            ok[j] = f2b(kcat[h][d] * rk * k_cat_nw[d]);
        }
        *reinterpret_cast<u16x8*>(&xq[(size_t)tok * DIM + h * 128 + sub*8]) = oq;
        *reinterpret_cast<u16x8*>(&xk[(size_t)tok * DIM + h * 128 + sub*8]) = ok;
    }
}

// ---------------- K4: V transpose -> xvT[b,h,d,s] ----------------
__global__ __launch_bounds__(256) void transpose_v(const unsigned short* __restrict__ xv,
                                                   unsigned short* __restrict__ xvT){
    __shared__ unsigned short tile[128][129];
    const int blk = blockIdx.x;
    const int st = blk & 15;
    const int bh = blk >> 4;
    const int b = bh >> 4, h = bh & 15;
    const int t = threadIdx.x;
    const int s0 = st * 128;
    #pragma unroll
    for (int i = 0; i < 8; ++i){
        int c = t + 256 * i;
        int r = c >> 4, dc = c & 15;
        u16x8 v = *reinterpret_cast<const u16x8*>(&xv[((size_t)(b*SS + s0 + r)) * DIM + h*HD + dc*8]);
        #pragma unroll
        for (int j = 0; j < 8; ++j) tile[r][dc*8 + j] = v[j];
    }
    __syncthreads();
    #pragma unroll
    for (int i = 0; i < 8; ++i){
        int c = t + 256 * i;
        int d = c >> 4, sc = c & 15;
        u16x8 o;
        #pragma unroll
        for (int j = 0; j < 8; ++j) o[j] = tile[sc*8 + j][d];
        *reinterpret_cast<u16x8*>(&xvT[((size_t)bh * HD + d) * SS + s0 + sc*8]) = o;
    }
}

// ---------------- K3: flash attention v2 — swapped QK^T, in-lane softmax ----------------
// grid 1024 = b(2) x h(16) x qt(32); block 256 = 4 waves x 16 q-rows
// S^T = MFMA(A=K, B=Q): col=l16 -> q (lane-owned), row=lq*4+r -> kv
// O^T = MFMA(A=V^T, B=P): col=l16 -> q  => alpha/1-over-l are lane-uniform
__global__ __launch_bounds__(256) void attn_fwd(const unsigned short* __restrict__ xq,
                                                const unsigned short* __restrict__ xk,
                                                const unsigned short* __restrict__ xvT,
                                                unsigned short* __restrict__ attn_out){
    __shared__ __attribute__((aligned(16))) unsigned short Kl[64 * 128];   // [kv][d] swizzled
    __shared__ __attribute__((aligned(16))) unsigned short Vt[128 * 64];   // [d][kv] swizzled
    __shared__ __attribute__((aligned(16))) unsigned short Pl[4][16 * 64]; // per-wave [q][kv] swizzled
    // XCD-aware swizzle: 1024 % 8 == 0, bijective
    const int blk = ((int)blockIdx.x & 7) * 128 + ((int)blockIdx.x >> 3);
    const int qt = blk & 31, h = (blk >> 5) & 15, b = blk >> 9;
    const int t = threadIdx.x, lane = t & 63, w = t >> 6;
    const int l16 = lane & 15, lq = lane >> 4;
    const float scale = 0.08838834764831845f;
    const int qbase = qt * 64 + w * 16;

    // Q B-fragments in registers: q-col = l16, k-dim d = ks*32 + lq*8 + j
    short8 qf[4];
    #pragma unroll
    for (int ks = 0; ks < 4; ++ks)
        qf[ks] = *reinterpret_cast<const short8*>(
            &xq[((size_t)(b*SS + qbase + l16)) * DIM + h*HD + ks*32 + lq*8]);

    float mrun = -INFINITY, lrun = 0.f;
    f32x4 O[8];
    const f32x4 z = {0.f, 0.f, 0.f, 0.f};
    #pragma unroll
    for (int dn = 0; dn < 8; ++dn) O[dn] = z;

    u16x8 kreg[4], vreg[4];
    const size_t kbase = (size_t)(b*SS) * DIM + h*HD;
    const size_t vbase = ((size_t)(b*NH + h)) * HD * SS;

    // --- prologue: load tile 0, store to LDS ---
    #pragma unroll
    for (int i = 0; i < 4; ++i){
        int c = t + 256 * i;
        kreg[i] = *reinterpret_cast<const u16x8*>(&xk[kbase + (size_t)(c >> 4) * DIM + (c & 15) * 8]);
        vreg[i] = *reinterpret_cast<const u16x8*>(&xvT[vbase + (size_t)(c >> 3) * SS + (c & 7) * 8]);
    }
    #pragma unroll
    for (int i = 0; i < 4; ++i){
        int c = t + 256 * i;
        int r = c >> 4, dc = c & 15;
        *reinterpret_cast<u16x8*>(&Kl[r*128 + ((dc ^ (r & 7)) * 8)]) = kreg[i];
        int d = c >> 3, kc = c & 7;
        *reinterpret_cast<u16x8*>(&Vt[d*64 + ((kc ^ (d & 7)) * 8)]) = vreg[i];
    }
    __syncthreads();

    unsigned short* P = Pl[w];

    for (int kt = 0; kt < SS/64; ++kt){
        const int more = (kt + 1) < SS/64;
        // T14: issue next tile's global loads early; consumed after compute
        if (more){
            #pragma unroll
            for (int i = 0; i < 4; ++i){
                int c = t + 256 * i;
                kreg[i] = *reinterpret_cast<const u16x8*>(
                    &xk[kbase + (size_t)((kt+1)*64 + (c >> 4)) * DIM + (c & 15) * 8]);
                vreg[i] = *reinterpret_cast<const u16x8*>(
                    &xvT[vbase + (size_t)(c >> 3) * SS + (kt+1)*64 + (c & 7) * 8]);
            }
        }

        // S^T[kn] = K(rows kn*16+l16... no: A row=l16 covers kv; per-lane rows lq*4+r) x Q
        f32x4 St[4];
        #pragma unroll
        for (int kn = 0; kn < 4; ++kn) St[kn] = z;
        __builtin_amdgcn_s_setprio(1);
        #pragma unroll
        for (int kn = 0; kn < 4; ++kn){
            int kr = kn*16 + l16;
            #pragma unroll
            for (int ks = 0; ks < 4; ++ks){
                short8 ak = *reinterpret_cast<const short8*>(
                    &Kl[kr*128 + (((ks*4 + lq) ^ (kr & 7)) * 8)]);
                St[kn] = MFMA16(ak, qf[ks], St[kn]);
            }
        }
        __builtin_amdgcn_s_setprio(0);

        // in-lane softmax for q = l16 (replicated across lq); kv values: kn*16 + lq*4 + r
        float mt = St[0][0];
        #pragma unroll
        for (int kn = 0; kn < 4; ++kn)
            mt = fmaxf(mt, fmaxf(fmaxf(St[kn][0], St[kn][1]), fmaxf(St[kn][2], St[kn][3])));
        mt = fmaxf(mt, __shfl_xor(mt, 16));
        mt = fmaxf(mt, __shfl_xor(mt, 32));
        mt *= scale;
        int defer = __all(mt - mrun <= 8.f);   // T13 defer-max (wave-uniform branch)
        if (!defer){
            float mnew = fmaxf(mrun, mt);
            float alpha = __expf(mrun - mnew);
            lrun *= alpha;
            #pragma unroll
            for (int dn = 0; dn < 8; ++dn) O[dn] *= alpha;
            mrun = mnew;
        }
        float psum = 0.f;
        uint2 pk[4];
        #pragma unroll
        for (int kn = 0; kn < 4; ++kn){
            float p0 = __expf(St[kn][0]*scale - mrun);
            float p1 = __expf(St[kn][1]*scale - mrun);
            float p2 = __expf(St[kn][2]*scale - mrun);
            float p3 = __expf(St[kn][3]*scale - mrun);
            psum += (p0 + p1) + (p2 + p3);
            pk[kn].x = (unsigned)f2b(p0) | ((unsigned)f2b(p1) << 16);
            pk[kn].y = (unsigned)f2b(p2) | ((unsigned)f2b(p3) << 16);
        }
        psum += __shfl_xor(psum, 16);
        psum += __shfl_xor(psum, 32);
        lrun += psum;

        // write P[q=l16][kv] packed (per-wave buffer, 2x 8B stores per kn)
        #pragma unroll
        for (int kn = 0; kn < 4; ++kn){
            int chunk = (kn*2 + (lq >> 1)) ^ (l16 & 7);
            *reinterpret_cast<uint2*>(&P[l16*64 + chunk*8 + (lq & 1)*4]) = pk[kn];
        }
        asm volatile("s_waitcnt lgkmcnt(0)" ::: "memory");
        __builtin_amdgcn_sched_barrier(0);

        // O^T += V^T x P
        __builtin_amdgcn_s_setprio(1);
        #pragma unroll
        for (int kk = 0; kk < 2; ++kk){
            short8 pb = *reinterpret_cast<const short8*>(
                &P[l16*64 + (((kk*4 + lq) ^ (l16 & 7)) * 8)]);
            #pragma unroll
            for (int dn = 0; dn < 8; ++dn){
                int dr = dn*16 + l16;
                short8 av = *reinterpret_cast<const short8*>(
                    &Vt[dr*64 + (((kk*4 + lq) ^ (dr & 7)) * 8)]);
                O[dn] = MFMA16(av, pb, O[dn]);
            }
        }
        __builtin_amdgcn_s_setprio(0);
        __syncthreads();

        if (more){
            #pragma unroll
            for (int i = 0; i < 4; ++i){
                int c = t + 256 * i;
                int r = c >> 4, dc = c & 15;
                *reinterpret_cast<u16x8*>(&Kl[r*128 + ((dc ^ (r & 7)) * 8)]) = kreg[i];
                int d = c >> 3, kc = c & 7;
                *reinterpret_cast<u16x8*>(&Vt[d*64 + ((kc ^ (d & 7)) * 8)]) = vreg[i];
            }
            __syncthreads();
        }
    }

    // epilogue: O^T[dn] row = d = dn*16+lq*4+r, col q = l16; divide by l (lane-uniform)
    float inv = 1.f / lrun;
    #pragma unroll
    for (int dn = 0; dn < 8; ++dn){
        u16x4 o4;
        #pragma unroll
        for (int r = 0; r < 4; ++r) o4[r] = f2b(O[dn][r] * inv);
        *reinterpret_cast<u16x4*>(
            &attn_out[((size_t)(b*SS + qbase + l16)) * DIM + h*HD + dn*16 + lq*4]) = o4;
    }
}

// ---------------- K5: bias + rmsnorm epilogue (bf16 proj input) ----------------
__global__ __launch_bounds__(256) void proj_norm(const unsigned short* __restrict__ proj,
                                                 const float* __restrict__ bias,
                                                 const float* __restrict__ w,
                                                 float* __restrict__ out){
    __shared__ float buf[DIM];
    __shared__ float rbuf[4];
    const int row = blockIdx.x;
    const int t = threadIdx.x;
    const int lane = t & 63, wv = t >> 6;
    float ssq = 0.f;
    #pragma unroll
    for (int i = 0; i < 8; ++i){
        int o = t + i * 256;
        float v = b2f(proj[(size_t)row * DIM + o]) + bias[o];
        buf[o] = v;
        ssq += v * v;
    }
    #pragma unroll
    for (int o = 32; o >= 1; o >>= 1) ssq += __shfl_xor(ssq, o);
    if (lane == 0) rbuf[wv] = ssq;
    __syncthreads();
    float tot = rbuf[0] + rbuf[1] + rbuf[2] + rbuf[3];
    float rr = rsqrtf(tot * (1.f / DIM) + EPS);
    #pragma unroll
    for (int i = 0; i < 8; ++i){
        int o = t + i * 256;
        out[(size_t)row * DIM + o] = buf[o] * rr * w[o];
    }
}

extern "C" void kernel_launch(void* const* d_in, const int* in_sizes, int n_in,
                              void* d_out, int out_size, void* d_ws, size_t ws_size,
                              hipStream_t stream)
{
    const float* local_c  = (const float*)d_in[0];
    const float* global_c = (const float*)d_in[1];
    const float* freqs    = (const float*)d_in[2];
    const float* W_lc     = (const float*)d_in[3];
    const float* W_gc     = (const float*)d_in[4];
    const float* q_lc_nw  = (const float*)d_in[5];
    const float* k_lc_nw  = (const float*)d_in[6];
    const float* q_gc_nw  = (const float*)d_in[7];
    const float* k_gc_nw  = (const float*)d_in[8];
    const float* q_cat_nw = (const float*)d_in[9];
    const float* k_cat_nw = (const float*)d_in[10];
    const float* W_lo     = (const float*)d_in[11];
    const float* b_lo     = (const float*)d_in[12];
    const float* lc_on_w  = (const float*)d_in[13];
    const float* W_go     = (const float*)d_in[14];
    const float* b_go     = (const float*)d_in[15];
    const float* gc_on_w  = (const float*)d_in[16];
    float* out = (float*)d_out;

    // ---- aliased workspace arena: 120 MB total ----
    char* ws = (char*)d_ws;
    const size_t SZ_WLO  = (size_t)DIM * DIM * 2;
    const size_t SZ_WLC  = (size_t)TOT * DIM * 2;
    const size_t SZ_TOK2 = (size_t)NTOK * DIM * 2;
    const size_t SZ_COMB = (size_t)NTOK * TOT * 2;

    unsigned short* Wlo_b  = (unsigned short*)(ws);
    unsigned short* Wgo_b  = (unsigned short*)(ws + SZ_WLO);
    char*           slotW  = ws + 2*SZ_WLO;
    unsigned short* Wlc_b  = (unsigned short*)(slotW);
    unsigned short* Wgc_b  = (unsigned short*)(slotW + SZ_WLC);
    unsigned short* xv     = (unsigned short*)(slotW);
    char*           slotE  = ws + 2*SZ_WLO + 2*SZ_WLC;
    char*           slotF  = slotE + SZ_TOK2;
    unsigned short* xb_lc  = (unsigned short*)slotE;
    unsigned short* xb_gc  = (unsigned short*)slotF;
    unsigned short* xq     = (unsigned short*)slotE;
    unsigned short* xk     = (unsigned short*)slotF;
    unsigned short* proj_lc= (unsigned short*)slotE;
    unsigned short* proj_gc= (unsigned short*)slotF;
    char*           slotG  = slotF + SZ_TOK2;
    char*           slotH  = slotG + SZ_COMB;
    unsigned short* comb_lc= (unsigned short*)slotG;
    unsigned short* comb_gc= (unsigned short*)slotH;
    unsigned short* xvT    = (unsigned short*)slotG;
    unsigned short* attn_o = (unsigned short*)slotH;
    (void)ws_size;

    cvt_f32_bf16<<<1024, 256, 0, stream>>>(local_c,  xb_lc, NTOK * DIM / 8);
    cvt_f32_bf16<<<1024, 256, 0, stream>>>(global_c, xb_gc, NTOK * DIM / 8);
    cvt_f32_bf16<<<1024, 256, 0, stream>>>(W_lc, Wlc_b, TOT * DIM / 8);
    cvt_f32_bf16<<<1024, 256, 0, stream>>>(W_gc, Wgc_b, TOT * DIM / 8);
    cvt_f32_bf16<<<1024, 256, 0, stream>>>(W_lo, Wlo_b, DIM * DIM / 8);
    cvt_f32_bf16<<<1024, 256, 0, stream>>>(W_go, Wgo_b, DIM * DIM / 8);

    dim3 g1(TOT / 128, NTOK / 128);
    gemm_nt<unsigned short><<<g1, 256, 0, stream>>>(xb_lc, Wlc_b, comb_lc, NTOK, TOT, DIM);
    gemm_nt<unsigned short><<<g1, 256, 0, stream>>>(xb_gc, Wgc_b, comb_gc, NTOK, TOT, DIM);

    qkv_post<<<NTOK, 256, 0, stream>>>(comb_lc, comb_gc, freqs,
                                       q_lc_nw, k_lc_nw, q_gc_nw, k_gc_nw,
                                       q_cat_nw, k_cat_nw, xq, xk, xv);

    transpose_v<<<512, 256, 0, stream>>>(xv, xvT);

    attn_fwd<<<1024, 256, 0, stream>>>(xq, xk, xvT, attn_o);

    dim3 g2(DIM / 128, NTOK / 128);
    gemm_nt<unsigned short><<<g2, 256, 0, stream>>>(attn_o, Wlo_b, proj_lc, NTOK, DIM, DIM);
    gemm_nt<unsigned short><<<g2, 256, 0, stream>>>(attn_o, Wgo_b, proj_gc, NTOK, DIM, DIM);

    proj_norm<<<NTOK, 256, 0, stream>>>(proj_lc, b_lo, lc_on_w, out);
    proj_norm<<<NTOK, 256, 0, stream>>>(proj_gc, b_go, gc_on_w, out + (size_t)NTOK * DIM);
}